// Round 10
// baseline (136.352 us; speedup 1.0000x reference)
//
#include <hip/hip_runtime.h>
#include <hip/hip_bf16.h>

typedef __attribute__((ext_vector_type(8))) short bf16x8;
typedef __attribute__((ext_vector_type(4))) float f32x4;

#define B_ 8
#define S_ 1024
#define R_ 16384
#define H_ 128
#define D_ 256     // input dim = 2H
#define F_ 384     // inter dim

__device__ __forceinline__ unsigned short f2bf(float x) {
    unsigned int u = __float_as_uint(x);
    u += 0x7FFF + ((u >> 16) & 1);   // round-to-nearest-even
    return (unsigned short)(u >> 16);
}

__device__ __forceinline__ unsigned pack2bf(float a, float b) {
    float2 t; t.x = a; t.y = b;
    __hip_bfloat162 h = __float22bfloat162_rn(t);   // v_cvt_pk_bf16_f32
    return *reinterpret_cast<unsigned*>(&h);
}

// One fused prep kernel: span fp32->bf16, W1 transpose+cvt, W2 transpose+cvt.
__global__ __launch_bounds__(256) void k_prep(const float* __restrict__ span,
                                              const float* __restrict__ W1,
                                              const float* __restrict__ W2,
                                              unsigned short* __restrict__ spanbf,
                                              unsigned short* __restrict__ W1T,
                                              unsigned short* __restrict__ W2T) {
    const int bid = blockIdx.x;
    const int t = threadIdx.x;
    if (bid < 1024) {
        int i = bid * 256 + t;
        float4 v = reinterpret_cast<const float4*>(span)[i];
        ushort4 o;
        o.x = f2bf(v.x); o.y = f2bf(v.y); o.z = f2bf(v.z); o.w = f2bf(v.w);
        reinterpret_cast<ushort4*>(spanbf)[i] = o;
    } else if (bid < 1408) {
        int i = (bid - 1024) * 256 + t;       // W1T[f][d] = W1[d][f]
        int d = i & 255, f = i >> 8;
        W1T[i] = f2bf(W1[d * F_ + f]);
    } else {
        int i = (bid - 1408) * 256 + t;       // W2T[o][f] = W2[f][o]
        int o = i / F_, f = i - o * F_;
        W2T[i] = f2bf(W2[f * H_ + o]);
    }
}

// R2-refined: 64 rows/block, 8 waves (512 threads), 16x16x32 MFMA (R2-proven
// mappings). LDS 48 KiB OVERLAPPED (R3-proven):
//   phase A: sA = buf[0..32K)  [64][256] bf16, stride 512 B, swz byte^=((m&7)<<4)
//   phase H: sH = buf[0..48K)  [64][384] bf16, stride 768 B, same swz
// 3 barriers: stage|L1reads ; L1reads|sHwrites ; sHwrites|L2reads.
// Decomposed swizzle addressing (R4-proven numerics): base e0 holds the
// lg/swz XOR in bits 4-6; kt parity flips bit 6 (^64); (kt>>1)*128 is a pure
// immediate add (bits>=7, no carry into 4-6). Loops stay ROLLED (R2-proven
// scheduling; R4's full unroll exposed W-latency).
// Layer 1: wave w owns f in [w*48,+48), all 64 rows; W1 streamed from L2.
// Layer 2: wave w owns o in [w*16,+16); W2 preloaded to regs (48 VGPR).
// Swapped mfma operands (W as A-operand): lane holds 4 consecutive f / o.
__global__ __launch_bounds__(512, 4) void k_main(
    const unsigned short* __restrict__ spanbf,
    const int* __restrict__ rel_ids,
    const unsigned short* __restrict__ W1T,
    const float* __restrict__ b1,
    const unsigned short* __restrict__ W2T,
    const float* __restrict__ b2,
    float* __restrict__ out)
{
    extern __shared__ char smem[];
    char* sA = smem;              // 32 KiB, dies after L1 k-loop (bar2)
    char* sH = smem;              // 48 KiB, overlaps sA, lives after bar2

    const int tid = threadIdx.x;
    const int blk = blockIdx.x;           // 0..2047
    const int m0  = blk << 6;             // first global row
    const int b   = m0 >> 14;             // batch
    const int r0  = m0 & 16383;

    const int w  = tid >> 6;   // wave 0..7
    const int l  = tid & 63;
    const int lr = l & 15;
    const int lg = l >> 4;

    // ---------------- stage A: gathered rel_reps (bf16) ----------------
    {
        const int m = tid >> 3;               // 0..63 local row
        const int e = tid & 7;                // eighth of the 512-B row
        const int2 ids = reinterpret_cast<const int2*>(rel_ids)[(b << 14) + r0 + m];
        const int idx = (e < 4) ? ids.x : ids.y;
        const uint4* src = reinterpret_cast<const uint4*>(
            spanbf + (((b << 10) + idx) << 7) + ((e & 3) << 5));
        const int base = m * 512 + e * 64;
        const int swz = (m & 7) << 4;
        #pragma unroll
        for (int j = 0; j < 4; ++j) {
            uint4 v = src[j];
            *reinterpret_cast<uint4*>(sA + ((base + j * 16) ^ swz)) = v;
        }
    }

    // decomposed L1 A-read bases (computed pre-barrier, off critical path)
    int aOff[4][2];
    #pragma unroll
    for (int mt = 0; mt < 4; ++mt) {
        const int m = mt * 16 + lr;
        const int swz = (m & 7) << 4;
        const int e0 = m * 512 + ((lg << 4) ^ (swz & 0x30)) + (swz & 0x40);
        aOff[mt][0] = e0;
        aOff[mt][1] = e0 ^ 64;
    }

    // bias fragments
    const int fb0 = w * 48 + lg * 4;
    const float4 bias1_0 = *reinterpret_cast<const float4*>(b1 + fb0);
    const float4 bias1_1 = *reinterpret_cast<const float4*>(b1 + fb0 + 16);
    const float4 bias1_2 = *reinterpret_cast<const float4*>(b1 + fb0 + 32);
    const int ob = w * 16 + lg * 4;
    const float4 bias2 = *reinterpret_cast<const float4*>(b2 + ob);

    __syncthreads();                         // bar1: sA ready

    // ---------------- layer 1: h^T tiles = W1slice @ A^T ----------------
    const unsigned short* w1p = W1T + (unsigned)(w * 48 + lr) * 256 + lg * 8;

    f32x4 acc[3][4];
    #pragma unroll
    for (int ft = 0; ft < 3; ++ft)
        #pragma unroll
        for (int mt = 0; mt < 4; ++mt) acc[ft][mt] = {0.f, 0.f, 0.f, 0.f};

    #pragma unroll 1
    for (int kp = 0; kp < 4; ++kp) {      // kt = kp*2 + k2, rolled (R2 scheduling)
        bf16x8 Af[4][2];
        #pragma unroll
        for (int mt = 0; mt < 4; ++mt) {
            #pragma unroll
            for (int k2 = 0; k2 < 2; ++k2)
                Af[mt][k2] = *reinterpret_cast<const bf16x8*>(
                    sA + aOff[mt][k2] + kp * 128);
        }
        #pragma unroll
        for (int ft = 0; ft < 3; ++ft) {
            #pragma unroll
            for (int k2 = 0; k2 < 2; ++k2) {
                bf16x8 Wf = *reinterpret_cast<const bf16x8*>(
                    w1p + ft * 4096 + kp * 64 + k2 * 32);
                #pragma unroll
                for (int mt = 0; mt < 4; ++mt)
                    acc[ft][mt] = __builtin_amdgcn_mfma_f32_16x16x32_bf16(
                        Wf, Af[mt][k2], acc[ft][mt], 0, 0, 0);
            }
        }
    }

    __syncthreads();                         // bar2: all sA reads complete

    // ---------------- epilogue 1: bias + relu -> sH (packed b64) ----------
    #pragma unroll
    for (int ft = 0; ft < 3; ++ft) {
        const int fb = w * 48 + ft * 16 + lg * 4;
        const float4 bias = (ft == 0) ? bias1_0 : (ft == 1) ? bias1_1 : bias1_2;
        #pragma unroll
        for (int mt = 0; mt < 4; ++mt) {
            float v0 = fmaxf(acc[ft][mt][0] + bias.x, 0.0f);
            float v1 = fmaxf(acc[ft][mt][1] + bias.y, 0.0f);
            float v2 = fmaxf(acc[ft][mt][2] + bias.z, 0.0f);
            float v3 = fmaxf(acc[ft][mt][3] + bias.w, 0.0f);
            uint2 p;
            p.x = pack2bf(v0, v1);
            p.y = pack2bf(v2, v3);
            const int m = mt * 16 + lr;
            *reinterpret_cast<uint2*>(
                sH + ((m * 768 + fb * 2) ^ ((m & 7) << 4))) = p;
        }
    }

    // preload W2 fragments (48 VGPR; acc dead now) + decomposed sH bases
    bf16x8 W2f[12];
    {
        const unsigned short* w2p = W2T + (unsigned)(w * 16 + lr) * 384 + lg * 8;
        #pragma unroll
        for (int kt = 0; kt < 12; ++kt)
            W2f[kt] = *reinterpret_cast<const bf16x8*>(w2p + kt * 32);
    }
    int hOff[4][2];
    #pragma unroll
    for (int mt = 0; mt < 4; ++mt) {
        const int m = mt * 16 + lr;
        const int swz = (m & 7) << 4;
        const int e0 = m * 768 + ((lg << 4) ^ (swz & 0x30)) + (swz & 0x40);
        hOff[mt][0] = e0;
        hOff[mt][1] = e0 ^ 64;
    }

    __syncthreads();                         // bar3: sH ready

    // ---------------- layer 2: out^T tiles = W2slice @ h^T ----------------
    f32x4 acc2[4];
    #pragma unroll
    for (int mt = 0; mt < 4; ++mt) acc2[mt] = {0.f, 0.f, 0.f, 0.f};

    #pragma unroll 1
    for (int kp = 0; kp < 6; ++kp) {      // kt = kp*2 + k2, rolled
        #pragma unroll
        for (int k2 = 0; k2 < 2; ++k2) {
            #pragma unroll
            for (int mt = 0; mt < 4; ++mt) {
                bf16x8 Hf = *reinterpret_cast<const bf16x8*>(
                    sH + hOff[mt][k2] + kp * 128);
                acc2[mt] = __builtin_amdgcn_mfma_f32_16x16x32_bf16(
                    W2f[kp * 2 + k2], Hf, acc2[mt], 0, 0, 0);
            }
        }
    }

    // ---------------- epilogue 2: bias + direct float4 stores ---------------
    float* outp = out + (long)m0 * 128;
    #pragma unroll
    for (int mt = 0; mt < 4; ++mt) {
        const int m = mt * 16 + lr;
        float4 v;
        v.x = acc2[mt][0] + bias2.x;
        v.y = acc2[mt][1] + bias2.y;
        v.z = acc2[mt][2] + bias2.z;
        v.w = acc2[mt][3] + bias2.w;
        *reinterpret_cast<float4*>(outp + m * 128 + ob) = v;
    }
}

extern "C" void kernel_launch(void* const* d_in, const int* in_sizes, int n_in,
                              void* d_out, int out_size, void* d_ws, size_t ws_size,
                              hipStream_t stream) {
    const float* span = (const float*)d_in[0];
    const int*   rel  = (const int*)d_in[1];
    const float* W1   = (const float*)d_in[2];
    const float* b1   = (const float*)d_in[3];
    const float* W2   = (const float*)d_in[4];
    const float* b2   = (const float*)d_in[5];
    float* out = (float*)d_out;

    unsigned short* spanbf = (unsigned short*)d_ws;        // 2 MiB
    unsigned short* W1T = spanbf + B_ * S_ * H_;           // 192 KiB
    unsigned short* W2T = W1T + D_ * F_;                   // 96 KiB

    k_prep<<<1600, 256, 0, stream>>>(span, W1, W2, spanbf, W1T, W2T);
    k_main<<<(B_ * R_) / 64, 512, 49152, stream>>>(spanbf, rel, W1T, b1, W2T, b2, out);
}